// Round 4
// baseline (252.522 us; speedup 1.0000x reference)
//
#include <hip/hip_runtime.h>

#define BATCH 4
#define CCH   512
#define NN    4096
#define MIDD  64

typedef unsigned short u16;
typedef unsigned int   u32;
typedef short s8v  __attribute__((ext_vector_type(8)));
typedef float f16v __attribute__((ext_vector_type(16)));
typedef unsigned int u4v __attribute__((ext_vector_type(4)));

__device__ __forceinline__ u16 f2bf(float f) {
  u32 u = __float_as_uint(f);
  u += 0x7fffu + ((u >> 16) & 1u);   // RTNE
  return (u16)(u >> 16);
}

// async global->LDS DMA, 16B per lane; dest = wave-uniform base + lane*16
__device__ __forceinline__ void g2lds16(const u16* g, u16* l) {
  __builtin_amdgcn_global_load_lds(
      (const __attribute__((address_space(1))) u32*)(const void*)g,
      (__attribute__((address_space(3))) u32*)(void*)l, 16, 0, 0);
}

// s_waitcnt imm (gfx9): vmcnt [3:0]+[15:14], expcnt [6:4]=7, lgkmcnt [11:8]
#define S_WAITCNT(vm, lgkm) \
  __builtin_amdgcn_s_waitcnt(((vm) & 15) | (((vm) >> 4) << 14) | (0x7 << 4) | ((lgkm) << 8))

// ---------------------------------------------------------------------------
// prep_w: Wb[640][512] bf16 = [Wq; Wk; Wv] fp32, converted once.
// ---------------------------------------------------------------------------
__global__ __launch_bounds__(256) void prep_w(
    const float* __restrict__ Wq, const float* __restrict__ Wk,
    const float* __restrict__ Wv, u16* __restrict__ Wb)
{
  int e = (blockIdx.x * 256 + threadIdx.x) * 8;
  const float* src;
  if (e < 64 * 512)       src = Wq + e;
  else if (e < 128 * 512) src = Wk + (e - 64 * 512);
  else                    src = Wv + (e - 128 * 512);
  float4 v0 = *(const float4*)src;
  float4 v1 = *(const float4*)(src + 4);
  uint4 p;
  p.x = (u32)f2bf(v0.x) | ((u32)f2bf(v0.y) << 16);
  p.y = (u32)f2bf(v0.z) | ((u32)f2bf(v0.w) << 16);
  p.z = (u32)f2bf(v1.x) | ((u32)f2bf(v1.y) << 16);
  p.w = (u32)f2bf(v1.z) | ((u32)f2bf(v1.w) << 16);
  *(uint4*)(Wb + e) = p;
}

// ---------------------------------------------------------------------------
// transpose_cast: xbT[b][n][c] (bf16) = x[b][c][n] (fp32). 64x64 tiles.
// ---------------------------------------------------------------------------
__global__ __launch_bounds__(256) void transpose_cast(
    const float* __restrict__ x, u16* __restrict__ xbT)
{
  const int b  = blockIdx.z;
  const int c0 = blockIdx.y * 64;
  const int n0 = blockIdx.x * 64;
  const int t  = threadIdx.x;
  __shared__ float ts[64 * 65];

  #pragma unroll
  for (int k = 0; k < 4; k++) {
    int idx = t + 256 * k;
    int cc = idx >> 4, n4 = idx & 15;
    float4 v = *(const float4*)&x[((size_t)(b * CCH + c0 + cc)) * NN + n0 + n4 * 4];
    float* p = &ts[cc * 65 + n4 * 4];
    p[0] = v.x; p[1] = v.y; p[2] = v.z; p[3] = v.w;
  }
  __syncthreads();

  const int n = t >> 2, cb = (t & 3) * 16;
  u16 tmp[16];
  #pragma unroll
  for (int j = 0; j < 16; j++) tmp[j] = f2bf(ts[(cb + j) * 65 + n]);
  u16* dst = &xbT[((size_t)b * NN + n0 + n) * CCH + c0 + cb];
  *(uint4*)&dst[0] = *(uint4*)&tmp[0];
  *(uint4*)&dst[8] = *(uint4*)&tmp[8];
}

// ---------------------------------------------------------------------------
// proj_gemm v4: all-DMA staging, BK=32, double-buffered ws+xs, raw barriers
// with vmcnt(5). V epilogue writes the fragment-tiled layout
// vF[b][jt][dg][ks][lane][8]: element (d, j) with d = dg*32 + (lane&31),
// j = jt*64 + ks*16 + (lane>>5)*8 + e.
// ---------------------------------------------------------------------------
__global__ __launch_bounds__(256, 2) void proj_gemm(
    const u16* __restrict__ xbT, const u16* __restrict__ Wb,
    const float* __restrict__ bq, const float* __restrict__ bk,
    const float* __restrict__ bv,
    u16* __restrict__ qT, u16* __restrict__ kT, u16* __restrict__ vF)
{
  const int b  = blockIdx.z;
  const int mt = blockIdx.y;
  const int n0 = blockIdx.x * 256;
  const int t  = threadIdx.x;
  const int ln = t & 31, hi = (t & 63) >> 5, w = t >> 6;
  const int l  = t & 63;
  const int l2 = l & 3, lr = l >> 2;        // DMA: phys block, row-in-group
  const int swc = (l2 ^ (lr & 3)) * 8;      // content col offset (u16)

  const int mrow0 = (mt < 8) ? (128 + mt * 64) : ((mt == 8) ? 0 : 64);
  const float* bias = (mt < 8) ? (bv + mt * 64) : ((mt == 8) ? bq : bk);

  __shared__ u16 ws[2][64 * 32];    // W chunk [m][c32], swizzled
  __shared__ u16 xs[2][256 * 32];   // x chunk [n][c32], swizzled

  const u16* xsrc = xbT + ((size_t)b * NN + n0 + w * 64 + lr) * CCH + swc;
  const u16* wsrc = Wb + (size_t)(mrow0 + w * 16 + lr) * 512 + swc;

  f16v acc[4];
  #pragma unroll
  for (int i = 0; i < 4; i++)
    #pragma unroll
    for (int r = 0; r < 16; r++) acc[i][r] = 0.f;

  #pragma unroll
  for (int i = 0; i < 4; i++)
    g2lds16(xsrc + (size_t)(16 * i) * CCH, &xs[0][(w * 64 + i * 16) * 32]);
  g2lds16(wsrc, &ws[0][w * 16 * 32]);

  for (int it = 0; it < 16; it++) {
    const int cur = it & 1, nxt = cur ^ 1;
    __builtin_amdgcn_s_barrier();
    const int c1 = ((it + 1) & 15) * 32;
    #pragma unroll
    for (int i = 0; i < 4; i++)
      g2lds16(xsrc + (size_t)(16 * i) * CCH + c1, &xs[nxt][(w * 64 + i * 16) * 32]);
    g2lds16(wsrc + c1, &ws[nxt][w * 16 * 32]);

    S_WAITCNT(5, 15);
    __builtin_amdgcn_s_barrier();

    #pragma unroll
    for (int ks = 0; ks < 2; ks++) {
      const int cb = ((2 * ks + hi) ^ (ln & 3)) << 3;
      s8v a0 = *(const s8v*)&ws[cur][(ln)           * 32 + cb];
      s8v a1 = *(const s8v*)&ws[cur][(32 + ln)      * 32 + cb];
      s8v b0 = *(const s8v*)&xs[cur][(w * 64 + ln)      * 32 + cb];
      s8v b1 = *(const s8v*)&xs[cur][(w * 64 + 32 + ln) * 32 + cb];
      acc[0] = __builtin_amdgcn_mfma_f32_32x32x16_bf16(a0, b0, acc[0], 0, 0, 0);
      acc[1] = __builtin_amdgcn_mfma_f32_32x32x16_bf16(a0, b1, acc[1], 0, 0, 0);
      acc[2] = __builtin_amdgcn_mfma_f32_32x32x16_bf16(a1, b0, acc[2], 0, 0, 0);
      acc[3] = __builtin_amdgcn_mfma_f32_32x32x16_bf16(a1, b1, acc[3], 0, 0, 0);
    }
  }

  S_WAITCNT(0, 0);
  __builtin_amdgcn_s_barrier();

  if (mt < 8) {
    // V epilogue: stage [64 m][256 n] in LDS (16B-chunk index XOR m&31),
    // then emit fragment-tiled vF with 1KB-per-wave coalesced stores.
    u16* xt = &xs[0][0];
    #pragma unroll
    for (int mi = 0; mi < 2; mi++)
      #pragma unroll
      for (int ni = 0; ni < 2; ni++) {
        f16v& a = acc[mi * 2 + ni];
        #pragma unroll
        for (int r = 0; r < 16; r++) {
          int row = (r & 3) + 8 * (r >> 2) + 4 * hi;
          int m   = mi * 32 + row;
          int nr  = w * 64 + ni * 32 + ln;
          int c8  = nr >> 3;
          xt[m * 256 + ((c8 ^ (m & 31)) << 3) + (nr & 7)] = f2bf(a[r] + bias[m]);
        }
      }
    __syncthreads();
    const int jt0 = n0 >> 6;
    const size_t dgb = ((size_t)b * 64 + jt0 + w) * 16 + mt * 2;
    #pragma unroll
    for (int mh = 0; mh < 2; mh++)
      #pragma unroll
      for (int ks = 0; ks < 4; ks++) {
        int c8 = w * 8 + ks * 2 + hi;
        int m  = mh * 32 + ln;
        s8v vv = *(const s8v*)&xt[m * 256 + ((c8 ^ ln) << 3)];
        *(s8v*)&vF[(((dgb + mh) * 4 + ks) * 64 + l) * 8] = vv;
      }
  } else {
    u16* dst = (mt == 8) ? qT : kT;
    u16* xt  = &xs[0][0];
    #pragma unroll
    for (int mi = 0; mi < 2; mi++)
      #pragma unroll
      for (int ni = 0; ni < 2; ni++) {
        f16v& a = acc[mi * 2 + ni];
        #pragma unroll
        for (int r = 0; r < 16; r++) {
          int row = (r & 3) + 8 * (r >> 2) + 4 * hi;
          int m   = mi * 32 + row;
          int nr  = w * 64 + ni * 32 + ln;
          xt[(nr << 6) + (((m >> 3) ^ (ln & 7)) << 3) + (m & 7)] = f2bf(a[r] + bias[m]);
        }
      }
    __syncthreads();
    const int r7 = t & 7;
    u16* drow = &dst[((size_t)b * NN + n0 + t) * 64];
    #pragma unroll
    for (int k = 0; k < 8; k++)
      *(uint4*)&drow[k * 8] = *(uint4*)&xt[(t << 6) + ((k ^ r7) << 3)];
  }
}

// ---------------------------------------------------------------------------
// MFMA flash attention v7: swapped QK (S = mfma(K,Q) -> lane holds q=ln,
// j in regs), in-register softmax using ONLY verified primitives
// (f2bf packing + __shfl_xor(32) half-wave exchange; no cvt_pk/permlane asm),
// V direct-to-register from vF, K triple-buffered via DMA ->
// ONE barrier per iteration. 24 KB LDS. Wave w: qh = w&1, dh = w>>1.
// ---------------------------------------------------------------------------
__global__ __launch_bounds__(256, 2) void attn_kernel(
    const u16* __restrict__ qT,   // [B][N][64] bf16
    const u16* __restrict__ kT,   // [B][N][64] bf16
    const u16* __restrict__ vF,   // [B][64 jt][16 dg][4 ks][64 l][8 e] bf16
    const float* __restrict__ x,  // [B][C][N] fp32
    const float* __restrict__ gamma,
    float* __restrict__ out)      // [B][C][N] fp32
{
  __shared__ u16 ksm[3][64 * 64];   // K tiles [j][c], swizzled, triple-buffer

  const int bx    = blockIdx.x;
  const int slot  = bx & 7;
  const int b     = slot >> 1;
  const int dbase = (slot & 1) * 256;
  const int i0    = (bx >> 3) * 64;
  const int t     = threadIdx.x;
  const int l     = t & 63, ln = l & 31, hi = l >> 5;
  const int w     = t >> 6;
  const int qh    = w & 1;          // q-half of this wave
  const int dh    = w >> 1;         // d-half (128 d) of this wave
  const int l3    = l & 7, lh3 = l >> 3;
  const int sw8   = (l3 ^ lh3) * 8;

  // Q as B-operand: lane holds Q[q = i0+qh*32+ln][c = ks*16 + hi*8 + e]
  s8v qfrag[4];
  {
    const u16* qp = qT + ((size_t)b * NN + i0 + qh * 32 + ln) * 64 + hi * 8;
    #pragma unroll
    for (int k = 0; k < 4; k++) qfrag[k] = *(const s8v*)(qp + 16 * k);
  }

  const u16* ksrc = kT + (size_t)b * NN * 64 + (size_t)(16 * w + lh3) * 64 + sw8;
  // fragment-tiled V: this wave needs dg = (slot&1)*8 + dh*4 + {0..3}
  const u16* vfb = vF + (size_t)b * (64 * 16 * 4 * 64 * 8);
  const int dgbase = (slot & 1) * 8 + dh * 4;

  f16v oacc[4];                     // [dgi] : 32 d x 32 q each
  #pragma unroll
  for (int i = 0; i < 4; i++)
    #pragma unroll
    for (int r = 0; r < 16; r++) oacc[i][r] = 0.f;
  float lsum = 0.f;

  // prologue: K(0)->buf0, K(1)->buf1
  #pragma unroll
  for (int i = 0; i < 2; i++)
    g2lds16(ksrc + (size_t)(8 * i) * 64, &ksm[0][(w * 2 + i) * 512]);
  #pragma unroll
  for (int i = 0; i < 2; i++)
    g2lds16(ksrc + (size_t)(64 + 8 * i) * 64, &ksm[1][(w * 2 + i) * 512]);

  int cur = 0, nx1 = 1, nx2 = 2;
  for (int it = 0; it < 64; it++) {
    // V(it): 16 x 1KB-contiguous loads, consumed by PV at iter end
    s8v vf[4][4];
    {
      const u16* vp = vfb + (size_t)(it * 16 + dgbase) * 2048 + l * 8;
      #pragma unroll
      for (int dgi = 0; dgi < 4; dgi++)
        #pragma unroll
        for (int ks = 0; ks < 4; ks++)
          vf[dgi][ks] = *(const s8v*)(vp + dgi * 2048 + ks * 512);
    }

    S_WAITCNT(16, 15);                    // K(it),K(it+1) landed; V(it) in flight
    __builtin_amdgcn_s_barrier();         // K(it) visible; buf[nx2] free

    // K(it+2) -> buf nx2 (its last readers, QK(it-1), finished pre-barrier)
    {
      const int j2 = ((it + 2) & 63) * 64;
      u16* kdst = &ksm[0][0] + nx2 * 4096 + (w * 2) * 512;
      #pragma unroll
      for (int i = 0; i < 2; i++)
        g2lds16(ksrc + (size_t)(j2 + 8 * i) * 64, kdst + i * 512);
    }

    // QK swapped: ssw[jh2] = S[j = jh2*32 + reg][q = qh*32 + ln]
    const u16* kcur = &ksm[0][0] + cur * 4096;
    f16v ssw[2];
    #pragma unroll
    for (int jh2 = 0; jh2 < 2; jh2++) {
      #pragma unroll
      for (int r = 0; r < 16; r++) ssw[jh2][r] = 0.f;
      #pragma unroll
      for (int ks = 0; ks < 4; ks++) {
        s8v kf = *(const s8v*)&kcur[(jh2 * 32 + ln) * 64 + (((2 * ks + hi) ^ l3) << 3)];
        ssw[jh2] = __builtin_amdgcn_mfma_f32_32x32x16_bf16(kf, qfrag[ks], ssw[jh2], 0, 0, 0);
      }
    }

    // in-register softmax -> PV B-fragments, verified primitives only:
    // reg r of half hi holds j = 32a2 + (r&3) + 8(r>>2) + 4hi.
    // pb[ks2] lane(hi,e) needs P[j = 16ks2 + 8hi + e][q=ln]:
    //   word wd   (e=2wd,2wd+1):  hi=0 <- own X;       hi=1 <- partner Y
    //   word wd+2 (e=4+2wd,..):   hi=0 <- partner X;   hi=1 <- own Y
    // where X = pack(pe[8b2+2wd], pe[8b2+2wd+1]), Y = pack(pe[8b2+4+2wd], ..+1)
    u4v pfq[4];                           // [ks2 = 2*a2 + b2][word]
    #pragma unroll
    for (int a2 = 0; a2 < 2; a2++) {
      float pe[16];
      #pragma unroll
      for (int r = 0; r < 16; r++) {
        pe[r] = __expf(ssw[a2][r]);
        lsum += pe[r];
      }
      #pragma unroll
      for (int b2 = 0; b2 < 2; b2++)
        #pragma unroll
        for (int wd = 0; wd < 2; wd++) {
          u32 X = (u32)f2bf(pe[8 * b2 + 2 * wd])
                | ((u32)f2bf(pe[8 * b2 + 2 * wd + 1]) << 16);
          u32 Y = (u32)f2bf(pe[8 * b2 + 4 + 2 * wd])
                | ((u32)f2bf(pe[8 * b2 + 4 + 2 * wd + 1]) << 16);
          u32 Xs = (u32)__shfl_xor((int)X, 32);
          u32 Ys = (u32)__shfl_xor((int)Y, 32);
          pfq[a2 * 2 + b2][wd]     = hi ? Ys : X;
          pfq[a2 * 2 + b2][wd + 2] = hi ? Y  : Xs;
        }
    }

    // PV: oacc[dgi] += V[dgi] * P
    #pragma unroll
    for (int ks = 0; ks < 4; ks++) {
      s8v pb = (s8v)pfq[ks];
      oacc[0] = __builtin_amdgcn_mfma_f32_32x32x16_bf16(vf[0][ks], pb, oacc[0], 0, 0, 0);
      oacc[1] = __builtin_amdgcn_mfma_f32_32x32x16_bf16(vf[1][ks], pb, oacc[1], 0, 0, 0);
      oacc[2] = __builtin_amdgcn_mfma_f32_32x32x16_bf16(vf[2][ks], pb, oacc[2], 0, 0, 0);
      oacc[3] = __builtin_amdgcn_mfma_f32_32x32x16_bf16(vf[3][ks], pb, oacc[3], 0, 0, 0);
    }

    int tmp = cur; cur = nx1; nx1 = nx2; nx2 = tmp;
  }

  S_WAITCNT(0, 0);                        // drain wrap K prefetches before exit

  // denominator: lane's lsum covers (j mod 8) in [4hi,4hi+4); partner has rest
  const float lt   = lsum + __shfl_xor(lsum, 32);
  const float linv = 1.0f / lt;
  const float g0   = gamma[0];
  const int   q    = i0 + qh * 32 + ln;
  #pragma unroll
  for (int dgi = 0; dgi < 4; dgi++) {
    f16v& a = oacc[dgi];
    #pragma unroll
    for (int r = 0; r < 16; r++) {
      int dl = dh * 128 + dgi * 32 + (r & 3) + 8 * (r >> 2) + 4 * hi;
      size_t idx = ((size_t)b * CCH + dbase + dl) * NN + q;
      out[idx] = g0 * a[r] * linv + x[idx];
    }
  }
}

// ---------------------------------------------------------------------------
extern "C" void kernel_launch(void* const* d_in, const int* in_sizes, int n_in,
                              void* d_out, int out_size, void* d_ws, size_t ws_size,
                              hipStream_t stream) {
  const float* x     = (const float*)d_in[0];
  const float* Wq    = (const float*)d_in[1];
  const float* bq    = (const float*)d_in[2];
  const float* Wk    = (const float*)d_in[3];
  const float* bk    = (const float*)d_in[4];
  const float* Wv    = (const float*)d_in[5];
  const float* bv    = (const float*)d_in[6];
  const float* gamma = (const float*)d_in[7];
  float* out = (float*)d_out;

  u16* qT  = (u16*)d_ws;                           // [B][N][64]   2 MB
  u16* kT  = qT  + (size_t)BATCH * NN * MIDD;      // [B][N][64]   2 MB
  u16* vF  = kT  + (size_t)BATCH * NN * MIDD;      // [B][64][16][4][64][8] 16.8 MB
  u16* xbT = vF  + (size_t)BATCH * CCH * NN;       // [B][N][C]   16.8 MB
  u16* Wb  = xbT + (size_t)BATCH * NN * CCH;       // [640][512]   0.66 MB

  prep_w<<<dim3(160), 256, 0, stream>>>(Wq, Wk, Wv, Wb);
  transpose_cast<<<dim3(NN / 64, CCH / 64, BATCH), 256, 0, stream>>>(x, xbT);
  proj_gemm<<<dim3(NN / 256, 10, BATCH), 256, 0, stream>>>(
      xbT, Wb, bq, bk, bv, qT, kT, vF);
  attn_kernel<<<dim3(512), 256, 0, stream>>>(qT, kT, vF, x, gamma, out);
}

// Round 5
// 239.789 us; speedup vs baseline: 1.0531x; 1.0531x over previous
//
#include <hip/hip_runtime.h>

#define BATCH 4
#define CCH   512
#define NN    4096
#define MIDD  64

typedef unsigned short u16;
typedef unsigned int   u32;
typedef short s8v  __attribute__((ext_vector_type(8)));
typedef float f16v __attribute__((ext_vector_type(16)));
typedef unsigned int u4v __attribute__((ext_vector_type(4)));

__device__ __forceinline__ u16 f2bf(float f) {
  u32 u = __float_as_uint(f);
  u += 0x7fffu + ((u >> 16) & 1u);   // RTNE
  return (u16)(u >> 16);
}

// async global->LDS DMA, 16B per lane; dest = wave-uniform base + lane*16
__device__ __forceinline__ void g2lds16(const u16* g, u16* l) {
  __builtin_amdgcn_global_load_lds(
      (const __attribute__((address_space(1))) u32*)(const void*)g,
      (__attribute__((address_space(3))) u32*)(void*)l, 16, 0, 0);
}

// s_waitcnt imm (gfx9): vmcnt [3:0]+[15:14], expcnt [6:4]=7, lgkmcnt [11:8]
#define S_WAITCNT(vm, lgkm) \
  __builtin_amdgcn_s_waitcnt(((vm) & 15) | (((vm) >> 4) << 14) | (0x7 << 4) | ((lgkm) << 8))

// ---------------------------------------------------------------------------
// prep_w: Wb[640][512] bf16 = [Wq; Wk; Wv] fp32, converted once.
// ---------------------------------------------------------------------------
__global__ __launch_bounds__(256) void prep_w(
    const float* __restrict__ Wq, const float* __restrict__ Wk,
    const float* __restrict__ Wv, u16* __restrict__ Wb)
{
  int e = (blockIdx.x * 256 + threadIdx.x) * 8;
  const float* src;
  if (e < 64 * 512)       src = Wq + e;
  else if (e < 128 * 512) src = Wk + (e - 64 * 512);
  else                    src = Wv + (e - 128 * 512);
  float4 v0 = *(const float4*)src;
  float4 v1 = *(const float4*)(src + 4);
  uint4 p;
  p.x = (u32)f2bf(v0.x) | ((u32)f2bf(v0.y) << 16);
  p.y = (u32)f2bf(v0.z) | ((u32)f2bf(v0.w) << 16);
  p.z = (u32)f2bf(v1.x) | ((u32)f2bf(v1.y) << 16);
  p.w = (u32)f2bf(v1.z) | ((u32)f2bf(v1.w) << 16);
  *(uint4*)(Wb + e) = p;
}

// ---------------------------------------------------------------------------
// transpose_cast: xbT[b][n][c] (bf16) = x[b][c][n] (fp32). 64x64 tiles.
// ---------------------------------------------------------------------------
__global__ __launch_bounds__(256) void transpose_cast(
    const float* __restrict__ x, u16* __restrict__ xbT)
{
  const int b  = blockIdx.z;
  const int c0 = blockIdx.y * 64;
  const int n0 = blockIdx.x * 64;
  const int t  = threadIdx.x;
  __shared__ float ts[64 * 65];

  #pragma unroll
  for (int k = 0; k < 4; k++) {
    int idx = t + 256 * k;
    int cc = idx >> 4, n4 = idx & 15;
    float4 v = *(const float4*)&x[((size_t)(b * CCH + c0 + cc)) * NN + n0 + n4 * 4];
    float* p = &ts[cc * 65 + n4 * 4];
    p[0] = v.x; p[1] = v.y; p[2] = v.z; p[3] = v.w;
  }
  __syncthreads();

  const int n = t >> 2, cb = (t & 3) * 16;
  u16 tmp[16];
  #pragma unroll
  for (int j = 0; j < 16; j++) tmp[j] = f2bf(ts[(cb + j) * 65 + n]);
  u16* dst = &xbT[((size_t)b * NN + n0 + n) * CCH + c0 + cb];
  *(uint4*)&dst[0] = *(uint4*)&tmp[0];
  *(uint4*)&dst[8] = *(uint4*)&tmp[8];
}

// ---------------------------------------------------------------------------
// proj_gemm v4: all-DMA staging, BK=32, double-buffered ws+xs, raw barriers
// with vmcnt(5). V epilogue writes the fragment-tiled layout
// vF[b][jt][dg][ks][lane][8]: element (d, j) with d = dg*32 + (lane&31),
// j = jt*64 + ks*16 + (lane>>5)*8 + e.
// ---------------------------------------------------------------------------
__global__ __launch_bounds__(256, 2) void proj_gemm(
    const u16* __restrict__ xbT, const u16* __restrict__ Wb,
    const float* __restrict__ bq, const float* __restrict__ bk,
    const float* __restrict__ bv,
    u16* __restrict__ qT, u16* __restrict__ kT, u16* __restrict__ vF)
{
  const int b  = blockIdx.z;
  const int mt = blockIdx.y;
  const int n0 = blockIdx.x * 256;
  const int t  = threadIdx.x;
  const int ln = t & 31, hi = (t & 63) >> 5, w = t >> 6;
  const int l  = t & 63;
  const int l2 = l & 3, lr = l >> 2;        // DMA: phys block, row-in-group
  const int swc = (l2 ^ (lr & 3)) * 8;      // content col offset (u16)

  const int mrow0 = (mt < 8) ? (128 + mt * 64) : ((mt == 8) ? 0 : 64);
  const float* bias = (mt < 8) ? (bv + mt * 64) : ((mt == 8) ? bq : bk);

  __shared__ u16 ws[2][64 * 32];    // W chunk [m][c32], swizzled
  __shared__ u16 xs[2][256 * 32];   // x chunk [n][c32], swizzled

  const u16* xsrc = xbT + ((size_t)b * NN + n0 + w * 64 + lr) * CCH + swc;
  const u16* wsrc = Wb + (size_t)(mrow0 + w * 16 + lr) * 512 + swc;

  f16v acc[4];
  #pragma unroll
  for (int i = 0; i < 4; i++)
    #pragma unroll
    for (int r = 0; r < 16; r++) acc[i][r] = 0.f;

  #pragma unroll
  for (int i = 0; i < 4; i++)
    g2lds16(xsrc + (size_t)(16 * i) * CCH, &xs[0][(w * 64 + i * 16) * 32]);
  g2lds16(wsrc, &ws[0][w * 16 * 32]);

  for (int it = 0; it < 16; it++) {
    const int cur = it & 1, nxt = cur ^ 1;
    __builtin_amdgcn_s_barrier();
    const int c1 = ((it + 1) & 15) * 32;
    #pragma unroll
    for (int i = 0; i < 4; i++)
      g2lds16(xsrc + (size_t)(16 * i) * CCH + c1, &xs[nxt][(w * 64 + i * 16) * 32]);
    g2lds16(wsrc + c1, &ws[nxt][w * 16 * 32]);

    S_WAITCNT(5, 15);
    __builtin_amdgcn_s_barrier();

    #pragma unroll
    for (int ks = 0; ks < 2; ks++) {
      const int cb = ((2 * ks + hi) ^ (ln & 3)) << 3;
      s8v a0 = *(const s8v*)&ws[cur][(ln)           * 32 + cb];
      s8v a1 = *(const s8v*)&ws[cur][(32 + ln)      * 32 + cb];
      s8v b0 = *(const s8v*)&xs[cur][(w * 64 + ln)      * 32 + cb];
      s8v b1 = *(const s8v*)&xs[cur][(w * 64 + 32 + ln) * 32 + cb];
      acc[0] = __builtin_amdgcn_mfma_f32_32x32x16_bf16(a0, b0, acc[0], 0, 0, 0);
      acc[1] = __builtin_amdgcn_mfma_f32_32x32x16_bf16(a0, b1, acc[1], 0, 0, 0);
      acc[2] = __builtin_amdgcn_mfma_f32_32x32x16_bf16(a1, b0, acc[2], 0, 0, 0);
      acc[3] = __builtin_amdgcn_mfma_f32_32x32x16_bf16(a1, b1, acc[3], 0, 0, 0);
    }
  }

  S_WAITCNT(0, 0);
  __builtin_amdgcn_s_barrier();

  if (mt < 8) {
    // V epilogue: stage [64 m][256 n] in LDS (16B-chunk index XOR m&31),
    // then emit fragment-tiled vF with 1KB-per-wave coalesced stores.
    u16* xt = &xs[0][0];
    #pragma unroll
    for (int mi = 0; mi < 2; mi++)
      #pragma unroll
      for (int ni = 0; ni < 2; ni++) {
        f16v& a = acc[mi * 2 + ni];
        #pragma unroll
        for (int r = 0; r < 16; r++) {
          int row = (r & 3) + 8 * (r >> 2) + 4 * hi;
          int m   = mi * 32 + row;
          int nr  = w * 64 + ni * 32 + ln;
          int c8  = nr >> 3;
          xt[m * 256 + ((c8 ^ (m & 31)) << 3) + (nr & 7)] = f2bf(a[r] + bias[m]);
        }
      }
    __syncthreads();
    const int jt0 = n0 >> 6;
    const size_t dgb = ((size_t)b * 64 + jt0 + w) * 16 + mt * 2;
    #pragma unroll
    for (int mh = 0; mh < 2; mh++)
      #pragma unroll
      for (int ks = 0; ks < 4; ks++) {
        int c8 = w * 8 + ks * 2 + hi;
        int m  = mh * 32 + ln;
        s8v vv = *(const s8v*)&xt[m * 256 + ((c8 ^ ln) << 3)];
        *(s8v*)&vF[(((dgb + mh) * 4 + ks) * 64 + l) * 8] = vv;
      }
  } else {
    u16* dst = (mt == 8) ? qT : kT;
    u16* xt  = &xs[0][0];
    #pragma unroll
    for (int mi = 0; mi < 2; mi++)
      #pragma unroll
      for (int ni = 0; ni < 2; ni++) {
        f16v& a = acc[mi * 2 + ni];
        #pragma unroll
        for (int r = 0; r < 16; r++) {
          int row = (r & 3) + 8 * (r >> 2) + 4 * hi;
          int m   = mi * 32 + row;
          int nr  = w * 64 + ni * 32 + ln;
          xt[(nr << 6) + (((m >> 3) ^ (ln & 7)) << 3) + (m & 7)] = f2bf(a[r] + bias[m]);
        }
      }
    __syncthreads();
    const int r7 = t & 7;
    u16* drow = &dst[((size_t)b * NN + n0 + t) * 64];
    #pragma unroll
    for (int k = 0; k < 8; k++)
      *(uint4*)&drow[k * 8] = *(uint4*)&xt[(t << 6) + ((k ^ r7) << 3)];
  }
}

// ---------------------------------------------------------------------------
// MFMA flash attention v8: v7 structure (swapped QK, in-register softmax,
// V direct from vF, K triple-buffered, 1 barrier/iter) with the P-packing
// VALU cost cut: v_cvt_pk_bf16_f32 (T12 recipe, D.lo=S0/D.hi=S1) replaces
// f2bf pairs, and a single shfl_xor per group replaces two (each lane sends
// what its partner needs: T = hi ? X : Y).
// ---------------------------------------------------------------------------
__global__ __launch_bounds__(256, 2) void attn_kernel(
    const u16* __restrict__ qT,   // [B][N][64] bf16
    const u16* __restrict__ kT,   // [B][N][64] bf16
    const u16* __restrict__ vF,   // [B][64 jt][16 dg][4 ks][64 l][8 e] bf16
    const float* __restrict__ x,  // [B][C][N] fp32
    const float* __restrict__ gamma,
    float* __restrict__ out)      // [B][C][N] fp32
{
  __shared__ u16 ksm[3][64 * 64];   // K tiles [j][c], swizzled, triple-buffer

  const int bx    = blockIdx.x;
  const int slot  = bx & 7;
  const int b     = slot >> 1;
  const int dbase = (slot & 1) * 256;
  const int i0    = (bx >> 3) * 64;
  const int t     = threadIdx.x;
  const int l     = t & 63, ln = l & 31, hi = l >> 5;
  const int w     = t >> 6;
  const int qh    = w & 1;          // q-half of this wave
  const int dh    = w >> 1;         // d-half (128 d) of this wave
  const int l3    = l & 7, lh3 = l >> 3;
  const int sw8   = (l3 ^ lh3) * 8;

  // Q as B-operand: lane holds Q[q = i0+qh*32+ln][c = ks*16 + hi*8 + e]
  s8v qfrag[4];
  {
    const u16* qp = qT + ((size_t)b * NN + i0 + qh * 32 + ln) * 64 + hi * 8;
    #pragma unroll
    for (int k = 0; k < 4; k++) qfrag[k] = *(const s8v*)(qp + 16 * k);
  }

  const u16* ksrc = kT + (size_t)b * NN * 64 + (size_t)(16 * w + lh3) * 64 + sw8;
  // fragment-tiled V: this wave needs dg = (slot&1)*8 + dh*4 + {0..3}
  const u16* vfb = vF + (size_t)b * (64 * 16 * 4 * 64 * 8);
  const int dgbase = (slot & 1) * 8 + dh * 4;

  f16v oacc[4];                     // [dgi] : 32 d x 32 q each
  #pragma unroll
  for (int i = 0; i < 4; i++)
    #pragma unroll
    for (int r = 0; r < 16; r++) oacc[i][r] = 0.f;
  float lsum = 0.f;

  // prologue: K(0)->buf0, K(1)->buf1
  #pragma unroll
  for (int i = 0; i < 2; i++)
    g2lds16(ksrc + (size_t)(8 * i) * 64, &ksm[0][(w * 2 + i) * 512]);
  #pragma unroll
  for (int i = 0; i < 2; i++)
    g2lds16(ksrc + (size_t)(64 + 8 * i) * 64, &ksm[1][(w * 2 + i) * 512]);

  int cur = 0, nx1 = 1, nx2 = 2;
  for (int it = 0; it < 64; it++) {
    // V(it): 16 x 1KB-contiguous loads, consumed by PV at iter end
    s8v vf[4][4];
    {
      const u16* vp = vfb + (size_t)(it * 16 + dgbase) * 2048 + l * 8;
      #pragma unroll
      for (int dgi = 0; dgi < 4; dgi++)
        #pragma unroll
        for (int ks = 0; ks < 4; ks++)
          vf[dgi][ks] = *(const s8v*)(vp + dgi * 2048 + ks * 512);
    }

    S_WAITCNT(16, 15);                    // K(it),K(it+1) landed; V(it) in flight
    __builtin_amdgcn_s_barrier();         // K(it) visible; buf[nx2] free

    // K(it+2) -> buf nx2 (its last readers, QK(it-1), finished pre-barrier)
    {
      const int j2 = ((it + 2) & 63) * 64;
      u16* kdst = &ksm[0][0] + nx2 * 4096 + (w * 2) * 512;
      #pragma unroll
      for (int i = 0; i < 2; i++)
        g2lds16(ksrc + (size_t)(j2 + 8 * i) * 64, kdst + i * 512);
    }

    // QK swapped: ssw[jh2] = S[j = jh2*32 + reg][q = qh*32 + ln]
    const u16* kcur = &ksm[0][0] + cur * 4096;
    f16v ssw[2];
    #pragma unroll
    for (int jh2 = 0; jh2 < 2; jh2++) {
      #pragma unroll
      for (int r = 0; r < 16; r++) ssw[jh2][r] = 0.f;
      #pragma unroll
      for (int ks = 0; ks < 4; ks++) {
        s8v kf = *(const s8v*)&kcur[(jh2 * 32 + ln) * 64 + (((2 * ks + hi) ^ l3) << 3)];
        ssw[jh2] = __builtin_amdgcn_mfma_f32_32x32x16_bf16(kf, qfrag[ks], ssw[jh2], 0, 0, 0);
      }
    }

    // in-register softmax -> PV B-fragments.
    // reg r of half hi holds j = 32a2 + (r&3) + 8(r>>2) + 4hi.
    // pb[ks2] lane(hi,e) needs P[j = 16ks2 + 8hi + e][q=ln]:
    //   word wd   (e=2wd,2wd+1):  hi=0 <- own X;       hi=1 <- partner Y
    //   word wd+2 (e=4+2wd,..):   hi=0 <- partner X;   hi=1 <- own Y
    // X = pk(pe[8b2+2wd], pe[8b2+2wd+1]), Y = pk(pe[8b2+4+2wd], ..+1).
    // Single-shfl: T = hi ? X : Y  (what the partner needs); R = shfl(T,32):
    //   h0 receives partner's X (Xs), h1 receives partner's Y (Ys).
    u4v pfq[4];                           // [ks2 = 2*a2 + b2][word]
    #pragma unroll
    for (int a2 = 0; a2 < 2; a2++) {
      float pe[16];
      #pragma unroll
      for (int r = 0; r < 16; r++) {
        pe[r] = __expf(ssw[a2][r]);
        lsum += pe[r];
      }
      #pragma unroll
      for (int b2 = 0; b2 < 2; b2++)
        #pragma unroll
        for (int wd = 0; wd < 2; wd++) {
          u32 X, Y;
          asm("v_cvt_pk_bf16_f32 %0, %1, %2"
              : "=v"(X) : "v"(pe[8 * b2 + 2 * wd]), "v"(pe[8 * b2 + 2 * wd + 1]));
          asm("v_cvt_pk_bf16_f32 %0, %1, %2"
              : "=v"(Y) : "v"(pe[8 * b2 + 4 + 2 * wd]), "v"(pe[8 * b2 + 4 + 2 * wd + 1]));
          u32 T = hi ? X : Y;
          u32 R = (u32)__shfl_xor((int)T, 32);
          pfq[a2 * 2 + b2][wd]     = hi ? R : X;
          pfq[a2 * 2 + b2][wd + 2] = hi ? Y : R;
        }
    }

    // PV: oacc[dgi] += V[dgi] * P
    #pragma unroll
    for (int ks = 0; ks < 4; ks++) {
      s8v pb = (s8v)pfq[ks];
      oacc[0] = __builtin_amdgcn_mfma_f32_32x32x16_bf16(vf[0][ks], pb, oacc[0], 0, 0, 0);
      oacc[1] = __builtin_amdgcn_mfma_f32_32x32x16_bf16(vf[1][ks], pb, oacc[1], 0, 0, 0);
      oacc[2] = __builtin_amdgcn_mfma_f32_32x32x16_bf16(vf[2][ks], pb, oacc[2], 0, 0, 0);
      oacc[3] = __builtin_amdgcn_mfma_f32_32x32x16_bf16(vf[3][ks], pb, oacc[3], 0, 0, 0);
    }

    int tmp = cur; cur = nx1; nx1 = nx2; nx2 = tmp;
  }

  S_WAITCNT(0, 0);                        // drain wrap K prefetches before exit

  // denominator: lane's lsum covers (j mod 8) in [4hi,4hi+4); partner has rest
  const float lt   = lsum + __shfl_xor(lsum, 32);
  const float linv = 1.0f / lt;
  const float g0   = gamma[0];
  const int   q    = i0 + qh * 32 + ln;
  #pragma unroll
  for (int dgi = 0; dgi < 4; dgi++) {
    f16v& a = oacc[dgi];
    #pragma unroll
    for (int r = 0; r < 16; r++) {
      int dl = dh * 128 + dgi * 32 + (r & 3) + 8 * (r >> 2) + 4 * hi;
      size_t idx = ((size_t)b * CCH + dbase + dl) * NN + q;
      out[idx] = g0 * a[r] * linv + x[idx];
    }
  }
}

// ---------------------------------------------------------------------------
extern "C" void kernel_launch(void* const* d_in, const int* in_sizes, int n_in,
                              void* d_out, int out_size, void* d_ws, size_t ws_size,
                              hipStream_t stream) {
  const float* x     = (const float*)d_in[0];
  const float* Wq    = (const float*)d_in[1];
  const float* bq    = (const float*)d_in[2];
  const float* Wk    = (const float*)d_in[3];
  const float* bk    = (const float*)d_in[4];
  const float* Wv    = (const float*)d_in[5];
  const float* bv    = (const float*)d_in[6];
  const float* gamma = (const float*)d_in[7];
  float* out = (float*)d_out;

  u16* qT  = (u16*)d_ws;                           // [B][N][64]   2 MB
  u16* kT  = qT  + (size_t)BATCH * NN * MIDD;      // [B][N][64]   2 MB
  u16* vF  = kT  + (size_t)BATCH * NN * MIDD;      // [B][64][16][4][64][8] 16.8 MB
  u16* xbT = vF  + (size_t)BATCH * CCH * NN;       // [B][N][C]   16.8 MB
  u16* Wb  = xbT + (size_t)BATCH * NN * CCH;       // [640][512]   0.66 MB

  prep_w<<<dim3(160), 256, 0, stream>>>(Wq, Wk, Wv, Wb);
  transpose_cast<<<dim3(NN / 64, CCH / 64, BATCH), 256, 0, stream>>>(x, xbT);
  proj_gemm<<<dim3(NN / 256, 10, BATCH), 256, 0, stream>>>(
      xbT, Wb, bq, bk, bv, qT, kT, vF);
  attn_kernel<<<dim3(512), 256, 0, stream>>>(qT, kT, vF, x, gamma, out);
}

// Round 6
// 231.200 us; speedup vs baseline: 1.0922x; 1.0371x over previous
//
#include <hip/hip_runtime.h>

#define BATCH 4
#define CCH   512
#define NN    4096
#define MIDD  64

typedef unsigned short u16;
typedef unsigned int   u32;
typedef short s8v  __attribute__((ext_vector_type(8)));
typedef float f16v __attribute__((ext_vector_type(16)));
typedef unsigned int u4v __attribute__((ext_vector_type(4)));

#define L2E 1.44269504088896340736f

__device__ __forceinline__ u16 f2bf(float f) {
  u32 u = __float_as_uint(f);
  u += 0x7fffu + ((u >> 16) & 1u);   // RTNE
  return (u16)(u >> 16);
}

// async global->LDS DMA, 16B per lane; dest = wave-uniform base + lane*16
__device__ __forceinline__ void g2lds16(const u16* g, u16* l) {
  __builtin_amdgcn_global_load_lds(
      (const __attribute__((address_space(1))) u32*)(const void*)g,
      (__attribute__((address_space(3))) u32*)(void*)l, 16, 0, 0);
}

// s_waitcnt imm (gfx9): vmcnt [3:0]+[15:14], expcnt [6:4]=7, lgkmcnt [11:8]
#define S_WAITCNT(vm, lgkm) \
  __builtin_amdgcn_s_waitcnt(((vm) & 15) | (((vm) >> 4) << 14) | (0x7 << 4) | ((lgkm) << 8))

// ---------------------------------------------------------------------------
// prep_w: Wb[640][512] bf16 = [Wq*log2e; Wk; Wv] fp32, converted once.
// Wq is pre-scaled by log2(e) so attn can use raw v_exp_f32 (2^x).
// ---------------------------------------------------------------------------
__global__ __launch_bounds__(256) void prep_w(
    const float* __restrict__ Wq, const float* __restrict__ Wk,
    const float* __restrict__ Wv, u16* __restrict__ Wb)
{
  int e = (blockIdx.x * 256 + threadIdx.x) * 8;
  const float* src;
  float sc = 1.0f;
  if (e < 64 * 512)       { src = Wq + e; sc = L2E; }
  else if (e < 128 * 512) src = Wk + (e - 64 * 512);
  else                    src = Wv + (e - 128 * 512);
  float4 v0 = *(const float4*)src;
  float4 v1 = *(const float4*)(src + 4);
  uint4 p;
  p.x = (u32)f2bf(sc * v0.x) | ((u32)f2bf(sc * v0.y) << 16);
  p.y = (u32)f2bf(sc * v0.z) | ((u32)f2bf(sc * v0.w) << 16);
  p.z = (u32)f2bf(sc * v1.x) | ((u32)f2bf(sc * v1.y) << 16);
  p.w = (u32)f2bf(sc * v1.z) | ((u32)f2bf(sc * v1.w) << 16);
  *(uint4*)(Wb + e) = p;
}

// ---------------------------------------------------------------------------
// transpose_cast: xbT[b][n][c] (bf16) = x[b][c][n] (fp32). 64x64 tiles.
// ---------------------------------------------------------------------------
__global__ __launch_bounds__(256) void transpose_cast(
    const float* __restrict__ x, u16* __restrict__ xbT)
{
  const int b  = blockIdx.z;
  const int c0 = blockIdx.y * 64;
  const int n0 = blockIdx.x * 64;
  const int t  = threadIdx.x;
  __shared__ float ts[64 * 65];

  #pragma unroll
  for (int k = 0; k < 4; k++) {
    int idx = t + 256 * k;
    int cc = idx >> 4, n4 = idx & 15;
    float4 v = *(const float4*)&x[((size_t)(b * CCH + c0 + cc)) * NN + n0 + n4 * 4];
    float* p = &ts[cc * 65 + n4 * 4];
    p[0] = v.x; p[1] = v.y; p[2] = v.z; p[3] = v.w;
  }
  __syncthreads();

  const int n = t >> 2, cb = (t & 3) * 16;
  u16 tmp[16];
  #pragma unroll
  for (int j = 0; j < 16; j++) tmp[j] = f2bf(ts[(cb + j) * 65 + n]);
  u16* dst = &xbT[((size_t)b * NN + n0 + n) * CCH + c0 + cb];
  *(uint4*)&dst[0] = *(uint4*)&tmp[0];
  *(uint4*)&dst[8] = *(uint4*)&tmp[8];
}

// ---------------------------------------------------------------------------
// proj_gemm v4: all-DMA staging, BK=32, double-buffered ws+xs, raw barriers
// with vmcnt(5). V epilogue writes the fragment-tiled layout
// vF[b][jt][dg][ks][lane][8]: element (d, j) with d = dg*32 + (lane&31),
// j = jt*64 + ks*16 + (lane>>5)*8 + e. bq is scaled by log2(e) (see prep_w).
// ---------------------------------------------------------------------------
__global__ __launch_bounds__(256, 2) void proj_gemm(
    const u16* __restrict__ xbT, const u16* __restrict__ Wb,
    const float* __restrict__ bq, const float* __restrict__ bk,
    const float* __restrict__ bv,
    u16* __restrict__ qT, u16* __restrict__ kT, u16* __restrict__ vF)
{
  const int b  = blockIdx.z;
  const int mt = blockIdx.y;
  const int n0 = blockIdx.x * 256;
  const int t  = threadIdx.x;
  const int ln = t & 31, hi = (t & 63) >> 5, w = t >> 6;
  const int l  = t & 63;
  const int l2 = l & 3, lr = l >> 2;        // DMA: phys block, row-in-group
  const int swc = (l2 ^ (lr & 3)) * 8;      // content col offset (u16)

  const int mrow0 = (mt < 8) ? (128 + mt * 64) : ((mt == 8) ? 0 : 64);
  const float* bias = (mt < 8) ? (bv + mt * 64) : ((mt == 8) ? bq : bk);
  const float bsc = (mt == 8) ? L2E : 1.0f;

  __shared__ u16 ws[2][64 * 32];    // W chunk [m][c32], swizzled
  __shared__ u16 xs[2][256 * 32];   // x chunk [n][c32], swizzled

  const u16* xsrc = xbT + ((size_t)b * NN + n0 + w * 64 + lr) * CCH + swc;
  const u16* wsrc = Wb + (size_t)(mrow0 + w * 16 + lr) * 512 + swc;

  f16v acc[4];
  #pragma unroll
  for (int i = 0; i < 4; i++)
    #pragma unroll
    for (int r = 0; r < 16; r++) acc[i][r] = 0.f;

  #pragma unroll
  for (int i = 0; i < 4; i++)
    g2lds16(xsrc + (size_t)(16 * i) * CCH, &xs[0][(w * 64 + i * 16) * 32]);
  g2lds16(wsrc, &ws[0][w * 16 * 32]);

  for (int it = 0; it < 16; it++) {
    const int cur = it & 1, nxt = cur ^ 1;
    __builtin_amdgcn_s_barrier();
    const int c1 = ((it + 1) & 15) * 32;
    #pragma unroll
    for (int i = 0; i < 4; i++)
      g2lds16(xsrc + (size_t)(16 * i) * CCH + c1, &xs[nxt][(w * 64 + i * 16) * 32]);
    g2lds16(wsrc + c1, &ws[nxt][w * 16 * 32]);

    S_WAITCNT(5, 15);
    __builtin_amdgcn_s_barrier();

    #pragma unroll
    for (int ks = 0; ks < 2; ks++) {
      const int cb = ((2 * ks + hi) ^ (ln & 3)) << 3;
      s8v a0 = *(const s8v*)&ws[cur][(ln)           * 32 + cb];
      s8v a1 = *(const s8v*)&ws[cur][(32 + ln)      * 32 + cb];
      s8v b0 = *(const s8v*)&xs[cur][(w * 64 + ln)      * 32 + cb];
      s8v b1 = *(const s8v*)&xs[cur][(w * 64 + 32 + ln) * 32 + cb];
      acc[0] = __builtin_amdgcn_mfma_f32_32x32x16_bf16(a0, b0, acc[0], 0, 0, 0);
      acc[1] = __builtin_amdgcn_mfma_f32_32x32x16_bf16(a0, b1, acc[1], 0, 0, 0);
      acc[2] = __builtin_amdgcn_mfma_f32_32x32x16_bf16(a1, b0, acc[2], 0, 0, 0);
      acc[3] = __builtin_amdgcn_mfma_f32_32x32x16_bf16(a1, b1, acc[3], 0, 0, 0);
    }
  }

  S_WAITCNT(0, 0);
  __builtin_amdgcn_s_barrier();

  if (mt < 8) {
    // V epilogue: stage [64 m][256 n] in LDS (16B-chunk index XOR m&31),
    // then emit fragment-tiled vF with 1KB-per-wave coalesced stores.
    u16* xt = &xs[0][0];
    #pragma unroll
    for (int mi = 0; mi < 2; mi++)
      #pragma unroll
      for (int ni = 0; ni < 2; ni++) {
        f16v& a = acc[mi * 2 + ni];
        #pragma unroll
        for (int r = 0; r < 16; r++) {
          int row = (r & 3) + 8 * (r >> 2) + 4 * hi;
          int m   = mi * 32 + row;
          int nr  = w * 64 + ni * 32 + ln;
          int c8  = nr >> 3;
          xt[m * 256 + ((c8 ^ (m & 31)) << 3) + (nr & 7)] = f2bf(a[r] + bias[m]);
        }
      }
    __syncthreads();
    const int jt0 = n0 >> 6;
    const size_t dgb = ((size_t)b * 64 + jt0 + w) * 16 + mt * 2;
    #pragma unroll
    for (int mh = 0; mh < 2; mh++)
      #pragma unroll
      for (int ks = 0; ks < 4; ks++) {
        int c8 = w * 8 + ks * 2 + hi;
        int m  = mh * 32 + ln;
        s8v vv = *(const s8v*)&xt[m * 256 + ((c8 ^ ln) << 3)];
        *(s8v*)&vF[(((dgb + mh) * 4 + ks) * 64 + l) * 8] = vv;
      }
  } else {
    u16* dst = (mt == 8) ? qT : kT;
    u16* xt  = &xs[0][0];
    #pragma unroll
    for (int mi = 0; mi < 2; mi++)
      #pragma unroll
      for (int ni = 0; ni < 2; ni++) {
        f16v& a = acc[mi * 2 + ni];
        #pragma unroll
        for (int r = 0; r < 16; r++) {
          int row = (r & 3) + 8 * (r >> 2) + 4 * hi;
          int m   = mi * 32 + row;
          int nr  = w * 64 + ni * 32 + ln;
          xt[(nr << 6) + (((m >> 3) ^ (ln & 7)) << 3) + (m & 7)] = f2bf(a[r] + bsc * bias[m]);
        }
      }
    __syncthreads();
    const int r7 = t & 7;
    u16* drow = &dst[((size_t)b * NN + n0 + t) * 64];
    #pragma unroll
    for (int k = 0; k < 8; k++)
      *(uint4*)&drow[k * 8] = *(uint4*)&xt[(t << 6) + ((k ^ r7) << 3)];
  }
}

// ---------------------------------------------------------------------------
// MFMA flash attention v9: no-duplication split. Wave (qh=w&1, dh=w>>1)
// computes QK + softmax ONLY for its own 32-j half (4 MFMA + 16 exp2),
// packs its two PV B-groups in-register (cvt_pk + single-shfl, v8-verified),
// then exchanges the other two groups with partner wave (w^2) through a
// small double-buffered LDS buffer. V direct from vF, K triple-buffered.
// 2 barriers/iter. 40 KB LDS. exp uses raw v_exp_f32 (Q pre-scaled by log2e).
// ---------------------------------------------------------------------------
__global__ __launch_bounds__(256, 2) void attn_kernel(
    const u16* __restrict__ qT,   // [B][N][64] bf16 (Q*log2e)
    const u16* __restrict__ kT,   // [B][N][64] bf16
    const u16* __restrict__ vF,   // [B][64 jt][16 dg][4 ks][64 l][8 e] bf16
    const float* __restrict__ x,  // [B][C][N] fp32
    const float* __restrict__ gamma,
    float* __restrict__ out)      // [B][C][N] fp32
{
  __shared__ u16 ksm[3][64 * 64];   // K tiles [j][c], swizzled, triple-buffer
  __shared__ u4v pex[2][512];       // P exchange: [buf][(w*2+g)*64 + lane]

  const int bx    = blockIdx.x;
  const int slot  = bx & 7;
  const int b     = slot >> 1;
  const int dbase = (slot & 1) * 256;
  const int i0    = (bx >> 3) * 64;
  const int t     = threadIdx.x;
  const int l     = t & 63, ln = l & 31, hi = l >> 5;
  const int w     = t >> 6;
  const int qh    = w & 1;          // q-half of this wave
  const int dh    = w >> 1;         // d-half (128 d) AND j-half of this wave
  const int l3    = l & 7, lh3 = l >> 3;
  const int sw8   = (l3 ^ lh3) * 8;

  // Q as B-operand: lane holds Q[q = i0+qh*32+ln][c = ks*16 + hi*8 + e]
  s8v qfrag[4];
  {
    const u16* qp = qT + ((size_t)b * NN + i0 + qh * 32 + ln) * 64 + hi * 8;
    #pragma unroll
    for (int k = 0; k < 4; k++) qfrag[k] = *(const s8v*)(qp + 16 * k);
  }

  const u16* ksrc = kT + (size_t)b * NN * 64 + (size_t)(16 * w + lh3) * 64 + sw8;
  // fragment-tiled V: this wave needs dg = (slot&1)*8 + dh*4 + {0..3}
  const u16* vfb = vF + (size_t)b * (64 * 16 * 4 * 64 * 8);
  const int dgbase = (slot & 1) * 8 + dh * 4;

  f16v oacc[4];                     // [dgi] : 32 d x 32 q each
  #pragma unroll
  for (int i = 0; i < 4; i++)
    #pragma unroll
    for (int r = 0; r < 16; r++) oacc[i][r] = 0.f;
  float lsum = 0.f;

  // prologue: K(0)->buf0, K(1)->buf1
  #pragma unroll
  for (int i = 0; i < 2; i++)
    g2lds16(ksrc + (size_t)(8 * i) * 64, &ksm[0][(w * 2 + i) * 512]);
  #pragma unroll
  for (int i = 0; i < 2; i++)
    g2lds16(ksrc + (size_t)(64 + 8 * i) * 64, &ksm[1][(w * 2 + i) * 512]);

  int cur = 0, nx1 = 1, nx2 = 2;
  for (int it = 0; it < 64; it++) {
    // V(it): 16 x 1KB-contiguous loads, consumed by PV at iter end
    s8v vf[4][4];
    {
      const u16* vp = vfb + (size_t)(it * 16 + dgbase) * 2048 + l * 8;
      #pragma unroll
      for (int dgi = 0; dgi < 4; dgi++)
        #pragma unroll
        for (int ks = 0; ks < 4; ks++)
          vf[dgi][ks] = *(const s8v*)(vp + dgi * 2048 + ks * 512);
    }

    S_WAITCNT(16, 15);                    // K(it),K(it+1) landed; V(it) in flight
    __builtin_amdgcn_s_barrier();         // B: K(it) visible; buf[nx2] free

    // K(it+2) -> buf nx2 (its last readers, QK(it-1), finished pre-barrier)
    {
      const int j2 = ((it + 2) & 63) * 64;
      u16* kdst = &ksm[0][0] + nx2 * 4096 + (w * 2) * 512;
      #pragma unroll
      for (int i = 0; i < 2; i++)
        g2lds16(ksrc + (size_t)(j2 + 8 * i) * 64, kdst + i * 512);
    }

    // QK for own j-half only: ssw = S[j = dh*32 + reg][q = qh*32 + ln]
    const u16* kcur = &ksm[0][0] + cur * 4096;
    f16v ssw;
    #pragma unroll
    for (int r = 0; r < 16; r++) ssw[r] = 0.f;
    #pragma unroll
    for (int ks = 0; ks < 4; ks++) {
      s8v kf = *(const s8v*)&kcur[(dh * 32 + ln) * 64 + (((2 * ks + hi) ^ l3) << 3)];
      ssw = __builtin_amdgcn_mfma_f32_32x32x16_bf16(kf, qfrag[ks], ssw, 0, 0, 0);
    }

    // in-register softmax for own half -> 2 PV B-groups (v8-verified pack):
    // reg r of half hi holds j = 32dh + (r&3) + 8(r>>2) + 4hi.
    // own[b2] = pb group ks2 = 2dh + b2 (j in [16ks2, 16ks2+16)).
    float pe[16];
    #pragma unroll
    for (int r = 0; r < 16; r++) {
      pe[r] = __builtin_amdgcn_exp2f(ssw[r]);   // Q pre-scaled by log2e
      lsum += pe[r];
    }
    u4v own[2];
    #pragma unroll
    for (int b2 = 0; b2 < 2; b2++)
      #pragma unroll
      for (int wd = 0; wd < 2; wd++) {
        u32 X, Y;
        asm("v_cvt_pk_bf16_f32 %0, %1, %2"
            : "=v"(X) : "v"(pe[8 * b2 + 2 * wd]), "v"(pe[8 * b2 + 2 * wd + 1]));
        asm("v_cvt_pk_bf16_f32 %0, %1, %2"
            : "=v"(Y) : "v"(pe[8 * b2 + 4 + 2 * wd]), "v"(pe[8 * b2 + 4 + 2 * wd + 1]));
        u32 T = hi ? X : Y;
        u32 R = (u32)__shfl_xor((int)T, 32);
        own[b2][wd]     = hi ? R : X;
        own[b2][wd + 2] = hi ? Y : R;
      }

    // exchange the two groups with partner wave (w^2, same qh, other j-half)
    const int pc = it & 1;
    pex[pc][(w * 2 + 0) * 64 + l] = own[0];
    pex[pc][(w * 2 + 1) * 64 + l] = own[1];
    S_WAITCNT(63, 0);                     // LDS writes done (vm stays in flight)
    __builtin_amdgcn_s_barrier();         // C: P halves visible
    u4v o0 = pex[pc][((w ^ 2) * 2 + 0) * 64 + l];
    u4v o1 = pex[pc][((w ^ 2) * 2 + 1) * 64 + l];

    // group selection is wave-uniform: dh=0 owns ks2{0,1}, dh=1 owns {2,3}
    s8v pb0 = (s8v)(dh ? o0 : own[0]);
    s8v pb1 = (s8v)(dh ? o1 : own[1]);
    s8v pb2 = (s8v)(dh ? own[0] : o0);
    s8v pb3 = (s8v)(dh ? own[1] : o1);

    // PV: oacc[dgi] += V[dgi][ks] * P[ks]
    #pragma unroll
    for (int dgi = 0; dgi < 4; dgi++) {
      oacc[dgi] = __builtin_amdgcn_mfma_f32_32x32x16_bf16(vf[dgi][0], pb0, oacc[dgi], 0, 0, 0);
      oacc[dgi] = __builtin_amdgcn_mfma_f32_32x32x16_bf16(vf[dgi][1], pb1, oacc[dgi], 0, 0, 0);
      oacc[dgi] = __builtin_amdgcn_mfma_f32_32x32x16_bf16(vf[dgi][2], pb2, oacc[dgi], 0, 0, 0);
      oacc[dgi] = __builtin_amdgcn_mfma_f32_32x32x16_bf16(vf[dgi][3], pb3, oacc[dgi], 0, 0, 0);
    }

    int tmp = cur; cur = nx1; nx1 = nx2; nx2 = tmp;
  }

  S_WAITCNT(0, 0);                        // drain wrap K prefetches
  __builtin_amdgcn_s_barrier();

  // denominator: in-wave (hi halves) then cross-wave (dh pair) via LDS
  float lw = lsum + __shfl_xor(lsum, 32); // own j-half total, per q = ln
  float* lred = (float*)&pex[0][0];       // [4 waves][32 q]
  if (hi == 0) lred[w * 32 + ln] = lw;
  S_WAITCNT(63, 0);
  __builtin_amdgcn_s_barrier();
  const float lt   = lred[w * 32 + ln] + lred[(w ^ 2) * 32 + ln];
  const float linv = 1.0f / lt;
  const float g0   = gamma[0];
  const int   q    = i0 + qh * 32 + ln;
  #pragma unroll
  for (int dgi = 0; dgi < 4; dgi++) {
    f16v& a = oacc[dgi];
    #pragma unroll
    for (int r = 0; r < 16; r++) {
      int dl = dh * 128 + dgi * 32 + (r & 3) + 8 * (r >> 2) + 4 * hi;
      size_t idx = ((size_t)b * CCH + dbase + dl) * NN + q;
      out[idx] = g0 * a[r] * linv + x[idx];
    }
  }
}

// ---------------------------------------------------------------------------
extern "C" void kernel_launch(void* const* d_in, const int* in_sizes, int n_in,
                              void* d_out, int out_size, void* d_ws, size_t ws_size,
                              hipStream_t stream) {
  const float* x     = (const float*)d_in[0];
  const float* Wq    = (const float*)d_in[1];
  const float* bq    = (const float*)d_in[2];
  const float* Wk    = (const float*)d_in[3];
  const float* bk    = (const float*)d_in[4];
  const float* Wv    = (const float*)d_in[5];
  const float* bv    = (const float*)d_in[6];
  const float* gamma = (const float*)d_in[7];
  float* out = (float*)d_out;

  u16* qT  = (u16*)d_ws;                           // [B][N][64]   2 MB
  u16* kT  = qT  + (size_t)BATCH * NN * MIDD;      // [B][N][64]   2 MB
  u16* vF  = kT  + (size_t)BATCH * NN * MIDD;      // [B][64][16][4][64][8] 16.8 MB
  u16* xbT = vF  + (size_t)BATCH * CCH * NN;       // [B][N][C]   16.8 MB
  u16* Wb  = xbT + (size_t)BATCH * NN * CCH;       // [640][512]   0.66 MB

  prep_w<<<dim3(160), 256, 0, stream>>>(Wq, Wk, Wv, Wb);
  transpose_cast<<<dim3(NN / 64, CCH / 64, BATCH), 256, 0, stream>>>(x, xbT);
  proj_gemm<<<dim3(NN / 256, 10, BATCH), 256, 0, stream>>>(
      xbT, Wb, bq, bk, bv, qT, kT, vF);
  attn_kernel<<<dim3(512), 256, 0, stream>>>(qT, kT, vF, x, gamma, out);
}